// Round 4
// baseline (1024.716 us; speedup 1.0000x reference)
//
#include <hip/hip_runtime.h>
#include <hip/hip_bf16.h>
#include <stdint.h>

// Problem constants (from reference): B=4, T=2048 -> N=8192 tokens
#define N_TOK 8192
#define C_DIM 1024
#define E_NUM 8
#define H_DIM 4096
#define ROWS_PAD 10240  // 8192 + 8*256 upper bound on per-expert 256-padded rows
#define HBLK 32         // blocks in histogram/scan phase (256 tokens each)
#define MT_MAX 40       // max total 256-row m-tiles = 8192/256 + 8

typedef __attribute__((ext_vector_type(8))) short bf16x8;
typedef __attribute__((ext_vector_type(4))) float f32x4;

// round-to-nearest-even fp32 -> bf16
static __device__ __forceinline__ unsigned short f2bf(float f) {
    union { float f; unsigned u; } v; v.f = f;
    unsigned r = (v.u + 0x7FFFu + ((v.u >> 16) & 1u)) >> 16;
    return (unsigned short)r;
}

// swizzled fragment read from the tile buffer: row r (A: 0..255, B: 256..511),
// 16B unit u = ks*4+hi, stored at unit u ^ (r&7)  (T2 XOR swizzle)
static __device__ __forceinline__ bf16x8 rfragn(const unsigned short* base, int r, int ks, int hi) {
    int u = (ks * 4 + hi) ^ (r & 7);
    return *(const bf16x8*)(base + r * 64 + u * 8);
}

// ---------------------------------------------------------------------------
// Transpose + cast: in [E][K][N] fp32 -> out [E][N][K] bf16. LDS-tiled.
// ---------------------------------------------------------------------------
#define TP_STRIDE 258
__global__ __launch_bounds__(256) void transpose_w(const float* __restrict__ in,
                                                   unsigned short* __restrict__ out,
                                                   int K, int N) {
    __shared__ unsigned short tile[64 * TP_STRIDE];   // 33 KB
    int e  = blockIdx.z;
    int n0 = blockIdx.x * 64;
    int k0 = blockIdx.y * 256;
    int t = threadIdx.x;
    int lane = t & 63;
    int w = t >> 6;

    const float* ip = in + (size_t)e * K * N + (size_t)k0 * N + n0 + lane;
    unsigned short* lrow = &tile[lane * TP_STRIDE];
#pragma unroll 8
    for (int i = 0; i < 64; i++) {
        int k = w * 64 + i;
        lrow[k] = f2bf(ip[(size_t)k * N]);
    }
    __syncthreads();

    unsigned short* op = out + (size_t)e * N * K + (size_t)n0 * K + k0;
    for (int j = 0; j < 16; j++) {
        int n = w * 16 + j;
        const unsigned* src = (const unsigned*)&tile[n * TP_STRIDE];
        unsigned* dst = (unsigned*)&op[(size_t)n * K];
        dst[lane]      = src[lane];
        dst[lane + 64] = src[lane + 64];
    }
}

// ---------------------------------------------------------------------------
// Router: one wave per token, fp64 accumulation. NO global atomics.
// ---------------------------------------------------------------------------
__global__ void router_kernel(const float* __restrict__ x, const float* __restrict__ Wr,
                              const float* __restrict__ br,
                              float* __restrict__ probs, int* __restrict__ eidx) {
    int n = blockIdx.x * 4 + (threadIdx.x >> 6);
    int lane = threadIdx.x & 63;
    const float* xr = x + (size_t)n * C_DIM;
    double acc[E_NUM];
#pragma unroll
    for (int e = 0; e < E_NUM; e++) acc[e] = 0.0;
    for (int i = 0; i < 16; i++) {
        int c = i * 64 + lane;
        float xv = xr[c];
        const float4* wr = (const float4*)(Wr + c * E_NUM);
        float4 w0 = wr[0], w1 = wr[1];
        acc[0] += (double)xv * w0.x; acc[1] += (double)xv * w0.y;
        acc[2] += (double)xv * w0.z; acc[3] += (double)xv * w0.w;
        acc[4] += (double)xv * w1.x; acc[5] += (double)xv * w1.y;
        acc[6] += (double)xv * w1.z; acc[7] += (double)xv * w1.w;
    }
#pragma unroll
    for (int e = 0; e < E_NUM; e++) {
#pragma unroll
        for (int o = 32; o > 0; o >>= 1) acc[e] += __shfl_xor(acc[e], o, 64);
    }
    if (lane == 0) {
        float l[E_NUM];
        for (int e = 0; e < E_NUM; e++) l[e] = (float)acc[e] + br[e];
        int arg = 0; float m = l[0];
        for (int e = 1; e < E_NUM; e++) if (l[e] > m) { m = l[e]; arg = e; }  // first-max
        float s = 0.f;
        for (int e = 0; e < E_NUM; e++) s += expf(l[e] - m);
        probs[n] = 1.0f / s;     // = exp(lmax-m)/sum
        eidx[n] = arg;
    }
}

// ---------------------------------------------------------------------------
// Phase 1: per-block expert histogram (LDS atomics only)
// ---------------------------------------------------------------------------
__global__ void hist_kernel(const int* __restrict__ eidx, int* __restrict__ blk_cnt) {
    __shared__ int lh[E_NUM];
    int t = threadIdx.x, b = blockIdx.x;
    if (t < E_NUM) lh[t] = 0;
    __syncthreads();
    atomicAdd(&lh[eidx[b * 256 + t]], 1);
    __syncthreads();
    if (t < E_NUM) blk_cnt[b * E_NUM + t] = lh[t];
}

// ---------------------------------------------------------------------------
// Finalize: totals, 256-padded segment offsets, per-block bases, aux loss.
// ---------------------------------------------------------------------------
__global__ void finalize_kernel(const int* __restrict__ blk_cnt, int* __restrict__ cnt,
                                int* __restrict__ seg, int* __restrict__ blockbase,
                                float* __restrict__ aux_out) {
    int e = threadIdx.x;           // 64 threads; lanes 0..7 own experts
    int c[HBLK];
    int tot = 0;
    if (e < E_NUM) {
#pragma unroll
        for (int b = 0; b < HBLK; b++) { c[b] = blk_cnt[b * E_NUM + e]; tot += c[b]; }
    }
    int pad = ((tot + 255) >> 8) << 8;     // 256-pad for the 256-row GEMM tiles
    int sg = 0;
#pragma unroll
    for (int j = 0; j < E_NUM; j++) {
        int pj = __shfl(pad, j, 64);
        if (j < e) sg += pj;
    }
    if (e < E_NUM) {
        cnt[e] = tot;
        seg[e] = sg;
        int run = sg;
#pragma unroll
        for (int b = 0; b < HBLK; b++) { blockbase[b * E_NUM + e] = run; run += c[b]; }
        float fr = (float)tot / (float)N_TOK - 1.0f / (float)E_NUM;
        float s = fr * fr;
#pragma unroll
        for (int o = 4; o > 0; o >>= 1) s += __shfl_xor(s, o, 64);
        if (e == 0) aux_out[0] = s / (float)E_NUM;
    }
}

// ---------------------------------------------------------------------------
// Phase 2: assign rows (LDS-atomic local rank + precomputed block base)
// ---------------------------------------------------------------------------
__global__ void gatherpos_kernel(const float* __restrict__ probs, const int* __restrict__ eidx,
                                 const int* __restrict__ blockbase, int* __restrict__ tok_row,
                                 int* __restrict__ inv_row, float* __restrict__ rowprob) {
    __shared__ int lh[E_NUM];
    int t = threadIdx.x, b = blockIdx.x;
    if (t < E_NUM) lh[t] = 0;
    __syncthreads();
    int n = b * 256 + t;
    int e = eidx[n];
    int lrank = atomicAdd(&lh[e], 1);
    int row = blockbase[b * E_NUM + e] + lrank;
    tok_row[n] = row;
    inv_row[row] = n;
    rowprob[row] = probs[n];
}

// ---------------------------------------------------------------------------
// Copy: cast x rows into expert-grouped bf16 buffer; one wave per token.
// ---------------------------------------------------------------------------
__global__ void copy_kernel(const float* __restrict__ x, const int* __restrict__ tok_row,
                            unsigned short* __restrict__ xg) {
    int n = blockIdx.x * 4 + (threadIdx.x >> 6);
    int lane = threadIdx.x & 63;
    int row = tok_row[n];
    const float4* xr = (const float4*)(x + (size_t)n * C_DIM);
    uint2* xgr = (uint2*)(xg + (size_t)row * C_DIM);
#pragma unroll
    for (int i = 0; i < 4; i++) {
        float4 v = xr[i * 64 + lane];
        uint2 p;
        p.x = (unsigned)f2bf(v.x) | ((unsigned)f2bf(v.y) << 16);
        p.y = (unsigned)f2bf(v.z) | ((unsigned)f2bf(v.w) << 16);
        xgr[i * 64 + lane] = p;
    }
}

// ---------------------------------------------------------------------------
// Grouped GEMM, 256x256, BK=64, 8 waves. REGISTER-STAGED pipeline (HK style):
// global_load_dwordx4 -> VGPR -> ds_write_b128 (swizzled dest), NO LDS-DMA.
// Rounds 2-3 proved hipcc orders global_load_lds categorically against all
// ds_reads (vmcnt drain every phase -> 487 TF regardless of schedule). With
// reg staging all cross-tile ordering is register dataflow the compiler
// tracks precisely: loads for tile t+2 issue during tile t, are consumed by
// ds_writes during tile t+1 (auto vmcnt-on-use ~1 tile later = latency
// hidden). One lgkmcnt(0)+s_barrier per K-tile (was 8 barriers/tile).
// LDS [2][512 rows][64 shorts]: rows 0..255 = A-tile, 256..511 = B-tile;
// 16B unit u of row r stored at u ^ (r&7) (write-side and read-side XOR,
// same involution; layout identical to rounds 2-3: 0 bank conflicts).
// ---------------------------------------------------------------------------
#define GLD(kt) do {                                                           \
    _Pragma("unroll")                                                          \
    for (int i_ = 0; i_ < 4; i_++) {                                           \
        Areg[i_] = *(const uint4*)(Ab + (size_t)(srow + i_ * 64) * KDIM + (kt) * 64 + scol); \
        Breg[i_] = *(const uint4*)(Bb + (size_t)(srow + i_ * 64) * KDIM + (kt) * 64 + scol); \
    } } while (0)

#define DSW(D) do {                                                            \
    _Pragma("unroll")                                                          \
    for (int i_ = 0; i_ < 4; i_++) {                                           \
        *(uint4*)&lds[D][(srow + i_ * 64) * 64 + sus]       = Areg[i_];        \
        *(uint4*)&lds[D][(256 + srow + i_ * 64) * 64 + sus] = Breg[i_];        \
    } } while (0)

#define FRAG_A(SB, MH) do {                                                    \
    _Pragma("unroll")                                                          \
    for (int i_ = 0; i_ < 4; i_++) {                                           \
        int r_ = (MH) * 128 + wm * 64 + i_ * 16 + (lane & 15);                 \
        af[i_][0] = rfragn(SB, r_, 0, hi);                                     \
        af[i_][1] = rfragn(SB, r_, 1, hi);                                     \
    } } while (0)

#define FRAG_B(SB, NH) do {                                                    \
    _Pragma("unroll")                                                          \
    for (int j_ = 0; j_ < 2; j_++) {                                           \
        int r_ = 256 + (NH) * 128 + wn * 32 + j_ * 16 + (lane & 15);           \
        bf[NH][j_][0] = rfragn(SB, r_, 0, hi);                                 \
        bf[NH][j_][1] = rfragn(SB, r_, 1, hi);                                 \
    } } while (0)

#define MMAQ(MH, NH) do {                                                      \
    __builtin_amdgcn_s_setprio(1);                                             \
    _Pragma("unroll")                                                          \
    for (int i_ = 0; i_ < 4; i_++) {                                           \
        _Pragma("unroll")                                                      \
        for (int j_ = 0; j_ < 2; j_++) {                                       \
            acc[MH][i_][NH][j_] = __builtin_amdgcn_mfma_f32_16x16x32_bf16(     \
                af[i_][0], bf[NH][j_][0], acc[MH][i_][NH][j_], 0, 0, 0);       \
            acc[MH][i_][NH][j_] = __builtin_amdgcn_mfma_f32_16x16x32_bf16(     \
                af[i_][1], bf[NH][j_][1], acc[MH][i_][NH][j_], 0, 0, 0);       \
        }                                                                      \
    }                                                                          \
    __builtin_amdgcn_s_setprio(0);                                             \
} while (0)

#define TILEBAR() do { asm volatile("s_waitcnt lgkmcnt(0)" ::: "memory");      \
                       __builtin_amdgcn_s_barrier(); } while (0)

template <int KDIM, int NDIM, int EPI>
__global__ __launch_bounds__(512, 2) void moe_gemm(
    const unsigned short* __restrict__ Ag, const unsigned short* __restrict__ Bt,
    const float* __restrict__ bias, unsigned short* __restrict__ hg,
    float* __restrict__ out, const int* __restrict__ cnt, const int* __restrict__ seg,
    const int* __restrict__ inv_row, const float* __restrict__ rowprob) {
    // map m-slot -> (expert, m-tile)
    int mt = blockIdx.y;
    int e;
    for (e = 0; e < E_NUM; e++) {
        int te = (cnt[e] + 255) >> 8;
        if (mt < te) break;
        mt -= te;
    }
    if (e >= E_NUM) return;
    int row0 = seg[e] + mt * 256;
    int col0 = blockIdx.x * 256;

    __shared__ unsigned short lds[2][512 * 64];   // 128 KB: 2 x (A 256 rows + B 256 rows)

    const unsigned short* Ab = Ag + (size_t)row0 * KDIM;
    const unsigned short* Bb = Bt + (size_t)e * NDIM * KDIM + (size_t)col0 * KDIM;

    int tid = threadIdx.x;
    int lane = tid & 63;
    int wv = tid >> 6;
    int wm = wv >> 2;        // 0..1
    int wn = wv & 3;         // 0..3
    int hi = lane >> 4;      // 0..3

    // staging geometry: thread owns rows {srow, srow+64, srow+128, srow+192},
    // 16B unit (tid&7); swizzled LDS unit is thread-constant.
    int srow = tid >> 3;                         // 0..63
    int scol = (tid & 7) * 8;                    // element offset (16B)
    int sus  = (((tid & 7) ^ (srow & 7))) * 8;   // swizzled unit offset

    f32x4 acc[2][4][2][2] = {};    // [MH][i][NH][j]
    bf16x8 af[4][2], bf[2][2][2];  // af[i][ks], bf[NH][j][ks]
    uint4 Areg[4], Breg[4];        // staging registers (tile in flight)

    const int NT = KDIM / 64;      // K-tiles

    // prologue: tile0 -> regs -> buf0; tile1 -> regs
    GLD(0);
    DSW(0);
    GLD(1);
    TILEBAR();

    for (int t = 0; t < NT; t++) {
        int d = t & 1, dn = d ^ 1;
        const unsigned short* sb = &lds[d][0];
        FRAG_A(sb, 0);
        FRAG_B(sb, 0);
        if (t + 1 < NT) DSW(dn);       // regs hold tile t+1; write into back buffer
        if (t + 2 < NT) GLD(t + 2);    // refill regs (consumed next tile)
        MMAQ(0, 0);
        FRAG_B(sb, 1);
        MMAQ(0, 1);
        FRAG_A(sb, 1);
        MMAQ(1, 0);
        MMAQ(1, 1);
        TILEBAR();
    }

    // epilogue; C/D layout: col = lane&15, row = (lane>>4)*4 + reg
    int cl = lane & 15, rq = (lane >> 4) << 2;
#pragma unroll
    for (int MH = 0; MH < 2; MH++)
#pragma unroll
    for (int i = 0; i < 4; i++)
#pragma unroll
    for (int NH = 0; NH < 2; NH++)
#pragma unroll
    for (int j = 0; j < 2; j++) {
        int gcol = col0 + NH * 128 + wn * 32 + j * 16 + cl;
        float b = bias[e * NDIM + gcol];
        int growb = row0 + MH * 128 + wm * 64 + i * 16 + rq;
#pragma unroll
        for (int r = 0; r < 4; r++) {
            int grow = growb + r;
            float v = acc[MH][i][NH][j][r] + b;
            if (EPI == 1) {
                v = 0.5f * v * (1.0f + erff(v * 0.70710678118654752f));  // exact gelu
                hg[(size_t)grow * NDIM + gcol] = f2bf(v);
            } else {
                int token = inv_row[grow];
                if (token >= 0) out[(size_t)token * NDIM + gcol] = rowprob[grow] * v;
            }
        }
    }
}

// ---------------------------------------------------------------------------
extern "C" void kernel_launch(void* const* d_in, const int* in_sizes, int n_in,
                              void* d_out, int out_size, void* d_ws, size_t ws_size,
                              hipStream_t stream) {
    const float* x  = (const float*)d_in[0];
    const float* Wr = (const float*)d_in[1];
    const float* br = (const float*)d_in[2];
    const float* W1 = (const float*)d_in[3];
    const float* b1 = (const float*)d_in[4];
    const float* W2 = (const float*)d_in[5];
    const float* b2 = (const float*)d_in[6];
    float* out = (float*)d_out;

    // workspace layout (~228.2 MB)
    char* ws = (char*)d_ws;
    unsigned short* W1t = (unsigned short*)ws;                        // [E][H][C] bf16, 64MB
    unsigned short* W2t = (unsigned short*)(ws + 67108864ull);        // [E][C][H] bf16, 64MB
    unsigned short* xg  = (unsigned short*)(ws + 134217728ull);       // [ROWS_PAD][C] bf16, 20MB
    unsigned short* hg  = (unsigned short*)(ws + 155189248ull);       // [ROWS_PAD][H] bf16, 80MB
    char* small = ws + 239075328ull;
    float* probs     = (float*)small;                        // 32KB
    int*   eidx      = (int*)(small + 32768);                // 32KB
    float* rowprob   = (float*)(small + 65536);              // 40KB
    int*   inv_row   = (int*)(small + 106496);               // 40KB
    int*   tok_row   = (int*)(small + 147456);               // 32KB
    int*   blk_cnt   = (int*)(small + 180224);               // 1KB
    int*   blockbase = blk_cnt + HBLK * E_NUM;               // 1KB
    int*   cnt       = blockbase + HBLK * E_NUM;             // 8
    int*   seg       = cnt + 8;                              // 8

    hipMemsetAsync(xg, 0, (size_t)ROWS_PAD * C_DIM * 2, stream);          // zero pads
    hipMemsetAsync(inv_row, 0xFF, ROWS_PAD * 4, stream);                  // -1

    // W1 [E][C][H] -> W1t [E][H][C] ; W2 [E][H][C] -> W2t [E][C][H]
    transpose_w<<<dim3(H_DIM / 64, C_DIM / 256, E_NUM), 256, 0, stream>>>(W1, W1t, C_DIM, H_DIM);
    transpose_w<<<dim3(C_DIM / 64, H_DIM / 256, E_NUM), 256, 0, stream>>>(W2, W2t, H_DIM, C_DIM);

    router_kernel<<<N_TOK / 4, 256, 0, stream>>>(x, Wr, br, probs, eidx);
    hist_kernel<<<HBLK, 256, 0, stream>>>(eidx, blk_cnt);
    finalize_kernel<<<1, 64, 0, stream>>>(blk_cnt, cnt, seg, blockbase,
                                          out + (size_t)N_TOK * C_DIM);
    gatherpos_kernel<<<HBLK, 256, 0, stream>>>(probs, eidx, blockbase, tok_row, inv_row, rowprob);
    copy_kernel<<<N_TOK / 4, 256, 0, stream>>>(x, tok_row, xg);

    // GEMM1: h = gelu(xg @ W1[e] + b1[e])   [rows x H], K=C
    moe_gemm<C_DIM, H_DIM, 1><<<dim3(H_DIM / 256, MT_MAX), 512, 0, stream>>>(
        xg, W1t, b1, hg, nullptr, cnt, seg, inv_row, rowprob);
    // GEMM2: out[token] = prob * (hg @ W2[e] + b2[e])   [rows x C], K=H
    moe_gemm<H_DIM, C_DIM, 2><<<dim3(C_DIM / 256, MT_MAX), 512, 0, stream>>>(
        hg, W2t, b2, nullptr, out, cnt, seg, inv_row, rowprob);
}